// Round 1
// baseline (2276.320 us; speedup 1.0000x reference)
//
#include <hip/hip_runtime.h>

using bf16x8 = __attribute__((ext_vector_type(8))) short;
using f32x4  = __attribute__((ext_vector_type(4))) float;
using us4    = __attribute__((ext_vector_type(4))) unsigned short;

__device__ __forceinline__ unsigned short f2bf(float f) {
    unsigned int u = __builtin_bit_cast(unsigned int, f);
    u += 0x7fffu + ((u >> 16) & 1u);   // RNE
    return (unsigned short)(u >> 16);
}
__device__ __forceinline__ float bf2f(unsigned short s) {
    unsigned int u = ((unsigned int)s) << 16;
    return __builtin_bit_cast(float, u);
}

// ---------------------------------------------------------------------------
// NT GEMM: Out[M,N] = A[M,K] @ B[N,K]^T (+bias (+addend)) * scale
// M=8192, N=1024, K=1024. 128x128 tile, BK=64, 256 threads (4 waves, 2x2).
// A_BF16: A is bf16 (row-major), else fp32 (converted during staging).
// OUT_FP32: write fp32 row-major to Out; else bf16 head-layout (B,H,L,DK)
//           with optional bf16 addend at the same index, then *scale.
// ---------------------------------------------------------------------------
template<int A_BF16, int OUT_FP32>
__global__ __launch_bounds__(256, 2)
void gemm_nt_kernel(const void* __restrict__ Ap, const float* __restrict__ Bp,
                    const float* __restrict__ bias,
                    const unsigned short* __restrict__ addend,
                    void* __restrict__ Outp, float scale)
{
    constexpr int LDA = 72;  // bf16 elems per LDS row (144 B: 16B-aligned, 2-way banks)
    __shared__ unsigned short As[128 * LDA];
    __shared__ unsigned short Bs[128 * LDA];

    const int tid = threadIdx.x;
    const int bn = blockIdx.x, bm = blockIdx.y;
    const int wid = tid >> 6, lane = tid & 63;
    const int qd = lane >> 4, ln = lane & 15;
    const int wm = (wid >> 1) * 64, wn = (wid & 1) * 64;

    f32x4 zero4 = {0.f, 0.f, 0.f, 0.f};
    f32x4 acc[4][4];
#pragma unroll
    for (int i = 0; i < 4; ++i)
#pragma unroll
        for (int j = 0; j < 4; ++j) acc[i][j] = zero4;

    const float* Af = (const float*)Ap;
    const unsigned short* Ab = (const unsigned short*)Ap;

    for (int kk = 0; kk < 1024; kk += 64) {
        // ---- stage A tile (128 x 64) ----
        if (A_BF16) {
#pragma unroll
            for (int it = 0; it < 4; ++it) {
                int idx = tid + it * 256;           // 1024 chunks of 8 bf16
                int r = idx >> 3, c8 = idx & 7;
                uint4 v = *(const uint4*)(Ab + (size_t)(bm * 128 + r) * 1024 + kk + c8 * 8);
                *(uint4*)(As + r * LDA + c8 * 8) = v;
            }
        } else {
#pragma unroll
            for (int it = 0; it < 8; ++it) {
                int idx = tid + it * 256;           // 2048 float4
                int r = idx >> 4, c4 = idx & 15;
                float4 v = *(const float4*)(Af + (size_t)(bm * 128 + r) * 1024 + kk + c4 * 4);
                us4 o = { f2bf(v.x), f2bf(v.y), f2bf(v.z), f2bf(v.w) };
                *(us4*)(As + r * LDA + c4 * 4) = o;
            }
        }
        // ---- stage B tile (128 x 64), always fp32 weights ----
#pragma unroll
        for (int it = 0; it < 8; ++it) {
            int idx = tid + it * 256;
            int r = idx >> 4, c4 = idx & 15;
            float4 v = *(const float4*)(Bp + (size_t)(bn * 128 + r) * 1024 + kk + c4 * 4);
            us4 o = { f2bf(v.x), f2bf(v.y), f2bf(v.z), f2bf(v.w) };
            *(us4*)(Bs + r * LDA + c4 * 4) = o;
        }
        __syncthreads();

#pragma unroll
        for (int ks = 0; ks < 2; ++ks) {
            bf16x8 af[4], bfr[4];
#pragma unroll
            for (int i = 0; i < 4; ++i)
                af[i] = *(const bf16x8*)(As + (wm + i * 16 + ln) * LDA + ks * 32 + qd * 8);
#pragma unroll
            for (int i = 0; i < 4; ++i)
                bfr[i] = *(const bf16x8*)(Bs + (wn + i * 16 + ln) * LDA + ks * 32 + qd * 8);
#pragma unroll
            for (int mi = 0; mi < 4; ++mi)
#pragma unroll
                for (int ni = 0; ni < 4; ++ni)
                    acc[mi][ni] = __builtin_amdgcn_mfma_f32_16x16x32_bf16(
                        af[mi], bfr[ni], acc[mi][ni], 0, 0, 0);
        }
        __syncthreads();
    }

    // ---- epilogue ----
#pragma unroll
    for (int mi = 0; mi < 4; ++mi) {
#pragma unroll
        for (int ni = 0; ni < 4; ++ni) {
            int ocol = bn * 128 + wn + ni * 16 + ln;
            float bv = bias[ocol];
#pragma unroll
            for (int r = 0; r < 4; ++r) {
                int orow = bm * 128 + wm + mi * 16 + qd * 4 + r;
                float v = acc[mi][ni][r] + bv;
                if (OUT_FP32) {
                    ((float*)Outp)[(size_t)orow * 1024 + ocol] = v;
                } else {
                    int b = orow >> 11, l = orow & 2047;
                    int h = ocol >> 6, dk = ocol & 63;
                    size_t oidx = ((size_t)(b * 16 + h) * 2048 + l) * 64 + dk;
                    if (addend) v += bf2f(addend[oidx]);
                    v *= scale;
                    ((unsigned short*)Outp)[oidx] = f2bf(v);
                }
            }
        }
    }
}

// ---------------------------------------------------------------------------
// Fused two-pass attention. Grid: (16 q-tiles, 64 b*h). 256 thr, 4 waves.
// Each wave owns 32 q-rows. Pass1: online row max/sum. Pass2: P = exp(S-m)/l,
// write attn (via LDS, coalesced) and accumulate O = P @ V.
// qh is pre-scaled by 1/sqrt(DK).
// ---------------------------------------------------------------------------
__global__ __launch_bounds__(256, 2)
void attn_kernel(const unsigned short* __restrict__ qh,
                 const unsigned short* __restrict__ kh,
                 const unsigned short* __restrict__ vh,
                 const int* __restrict__ mask,
                 float* __restrict__ attn,
                 unsigned short* __restrict__ Og)
{
    constexpr int LKS = 72;    // K tile: [128][64] + pad
    constexpr int LVS = 136;   // V^T tile: [64][128] + pad
    constexpr int LPS = 136;   // P tile: [128][128] + pad
    __shared__ unsigned short Ks[128 * LKS];
    __shared__ unsigned short Vts[64 * LVS];
    __shared__ unsigned short Ps[128 * LPS];

    const int tid = threadIdx.x;
    const int qt = blockIdx.x;   // q tile 0..15
    const int bh = blockIdx.y;   // 0..63
    const int b = bh >> 4, h = bh & 15;
    const int wid = tid >> 6, lane = tid & 63;
    const int qd = lane >> 4, ln = lane & 15;

    const size_t head_off = (size_t)bh * 2048 * 64;
    const unsigned short* qbase = qh + head_off + (size_t)(qt * 128 + wid * 32) * 64;
    const unsigned short* kbase = kh + head_off;
    const unsigned short* vbase = vh + head_off;
    const int* maskb = mask + b * 2048;

    // Q fragments live in registers for the whole kernel
    bf16x8 aq[2][2];
#pragma unroll
    for (int mi = 0; mi < 2; ++mi)
#pragma unroll
        for (int ks = 0; ks < 2; ++ks)
            aq[mi][ks] = *(const bf16x8*)(qbase + (mi * 16 + ln) * 64 + ks * 32 + qd * 8);

    float mrow[2][4], lrow[2][4];
#pragma unroll
    for (int mi = 0; mi < 2; ++mi)
#pragma unroll
        for (int r = 0; r < 4; ++r) { mrow[mi][r] = -1e30f; lrow[mi][r] = 0.f; }

    f32x4 zero4 = {0.f, 0.f, 0.f, 0.f};

    // ================= pass 1: row max / sum =================
    for (int kt = 0; kt < 16; ++kt) {
#pragma unroll
        for (int it = 0; it < 4; ++it) {
            int idx = tid + it * 256;
            int r = idx >> 3, c8 = idx & 7;
            *(uint4*)(Ks + r * LKS + c8 * 8) =
                *(const uint4*)(kbase + (size_t)(kt * 128 + r) * 64 + c8 * 8);
        }
        __syncthreads();

        f32x4 s[2][8];
#pragma unroll
        for (int mi = 0; mi < 2; ++mi)
#pragma unroll
            for (int ni = 0; ni < 8; ++ni) s[mi][ni] = zero4;
#pragma unroll
        for (int ks = 0; ks < 2; ++ks) {
            bf16x8 bk[8];
#pragma unroll
            for (int ni = 0; ni < 8; ++ni)
                bk[ni] = *(const bf16x8*)(Ks + (ni * 16 + ln) * LKS + ks * 32 + qd * 8);
#pragma unroll
            for (int mi = 0; mi < 2; ++mi)
#pragma unroll
                for (int ni = 0; ni < 8; ++ni)
                    s[mi][ni] = __builtin_amdgcn_mfma_f32_16x16x32_bf16(
                        aq[mi][ks], bk[ni], s[mi][ni], 0, 0, 0);
        }
#pragma unroll
        for (int ni = 0; ni < 8; ++ni) {
            int mval = maskb[kt * 128 + ni * 16 + ln];
            if (mval == 0) {
#pragma unroll
                for (int mi = 0; mi < 2; ++mi)
#pragma unroll
                    for (int r = 0; r < 4; ++r) s[mi][ni][r] = -1e9f;
            }
        }
#pragma unroll
        for (int mi = 0; mi < 2; ++mi) {
#pragma unroll
            for (int r = 0; r < 4; ++r) {
                float tm = s[mi][0][r];
#pragma unroll
                for (int ni = 1; ni < 8; ++ni) tm = fmaxf(tm, s[mi][ni][r]);
                tm = fmaxf(tm, __shfl_xor(tm, 1));
                tm = fmaxf(tm, __shfl_xor(tm, 2));
                tm = fmaxf(tm, __shfl_xor(tm, 4));
                tm = fmaxf(tm, __shfl_xor(tm, 8));
                float mn = fmaxf(mrow[mi][r], tm);
                float ss = 0.f;
#pragma unroll
                for (int ni = 0; ni < 8; ++ni) ss += __expf(s[mi][ni][r] - mn);
                ss += __shfl_xor(ss, 1);
                ss += __shfl_xor(ss, 2);
                ss += __shfl_xor(ss, 4);
                ss += __shfl_xor(ss, 8);
                lrow[mi][r] = lrow[mi][r] * __expf(mrow[mi][r] - mn) + ss;
                mrow[mi][r] = mn;
            }
        }
        __syncthreads();
    }

    float rl[2][4];
#pragma unroll
    for (int mi = 0; mi < 2; ++mi)
#pragma unroll
        for (int r = 0; r < 4; ++r) rl[mi][r] = 1.0f / lrow[mi][r];

    f32x4 oacc[2][4];
#pragma unroll
    for (int mi = 0; mi < 2; ++mi)
#pragma unroll
        for (int nt = 0; nt < 4; ++nt) oacc[mi][nt] = zero4;

    float* attnb = attn + (size_t)bh * 2048 * 2048;

    // ================= pass 2: P write + P@V =================
    for (int kt = 0; kt < 16; ++kt) {
#pragma unroll
        for (int it = 0; it < 4; ++it) {
            int idx = tid + it * 256;
            int r = idx >> 3, c8 = idx & 7;
            *(uint4*)(Ks + r * LKS + c8 * 8) =
                *(const uint4*)(kbase + (size_t)(kt * 128 + r) * 64 + c8 * 8);
        }
        // V^T staging: coalesced global reads (consecutive dk), b64 LDS writes
#pragma unroll
        for (int it = 0; it < 4; ++it) {
            int idx = tid + it * 256;             // 1024 units: (ro 0..15, dk 0..63)
            int dk = idx & 63, ro = idx >> 6;
            unsigned short tmp[8];
#pragma unroll
            for (int j = 0; j < 8; ++j)
                tmp[j] = vbase[(size_t)(kt * 128 + ro * 8 + j) * 64 + dk];
            us4 w0 = { tmp[0], tmp[1], tmp[2], tmp[3] };
            us4 w1 = { tmp[4], tmp[5], tmp[6], tmp[7] };
            *(us4*)(Vts + dk * LVS + ro * 8) = w0;
            *(us4*)(Vts + dk * LVS + ro * 8 + 4) = w1;
        }
        __syncthreads();

        f32x4 s[2][8];
#pragma unroll
        for (int mi = 0; mi < 2; ++mi)
#pragma unroll
            for (int ni = 0; ni < 8; ++ni) s[mi][ni] = zero4;
#pragma unroll
        for (int ks = 0; ks < 2; ++ks) {
            bf16x8 bk[8];
#pragma unroll
            for (int ni = 0; ni < 8; ++ni)
                bk[ni] = *(const bf16x8*)(Ks + (ni * 16 + ln) * LKS + ks * 32 + qd * 8);
#pragma unroll
            for (int mi = 0; mi < 2; ++mi)
#pragma unroll
                for (int ni = 0; ni < 8; ++ni)
                    s[mi][ni] = __builtin_amdgcn_mfma_f32_16x16x32_bf16(
                        aq[mi][ks], bk[ni], s[mi][ni], 0, 0, 0);
        }
#pragma unroll
        for (int ni = 0; ni < 8; ++ni) {
            int mval = maskb[kt * 128 + ni * 16 + ln];
            if (mval == 0) {
#pragma unroll
                for (int mi = 0; mi < 2; ++mi)
#pragma unroll
                    for (int r = 0; r < 4; ++r) s[mi][ni][r] = -1e9f;
            }
        }
        // P = exp(S - m) / l  -> Ps (bf16)
#pragma unroll
        for (int mi = 0; mi < 2; ++mi)
#pragma unroll
            for (int r = 0; r < 4; ++r) {
                float mm = mrow[mi][r], rr = rl[mi][r];
                int prow = wid * 32 + mi * 16 + qd * 4 + r;
#pragma unroll
                for (int ni = 0; ni < 8; ++ni) {
                    float p = __expf(s[mi][ni][r] - mm) * rr;
                    Ps[prow * LPS + ni * 16 + ln] = f2bf(p);
                }
            }
        __syncthreads();

        // P @ V  (A from Ps own-wave rows, B from Vts)
#pragma unroll
        for (int ks = 0; ks < 4; ++ks) {
            bf16x8 ap[2], bv[4];
#pragma unroll
            for (int mi = 0; mi < 2; ++mi)
                ap[mi] = *(const bf16x8*)(Ps + (wid * 32 + mi * 16 + ln) * LPS + ks * 32 + qd * 8);
#pragma unroll
            for (int nt = 0; nt < 4; ++nt)
                bv[nt] = *(const bf16x8*)(Vts + (nt * 16 + ln) * LVS + ks * 32 + qd * 8);
#pragma unroll
            for (int mi = 0; mi < 2; ++mi)
#pragma unroll
                for (int nt = 0; nt < 4; ++nt)
                    oacc[mi][nt] = __builtin_amdgcn_mfma_f32_16x16x32_bf16(
                        ap[mi], bv[nt], oacc[mi][nt], 0, 0, 0);
        }

        // coalesced attn write from Ps (fp32)
        {
            int row = tid >> 1, half = tid & 1;
            const unsigned short* prow = Ps + row * LPS + half * 64;
            float* arow = attnb + (size_t)(qt * 128 + row) * 2048 + kt * 128 + half * 64;
#pragma unroll
            for (int c = 0; c < 64; c += 4) {
                float4 o = { bf2f(prow[c]), bf2f(prow[c + 1]),
                             bf2f(prow[c + 2]), bf2f(prow[c + 3]) };
                *(float4*)(arow + c) = o;
            }
        }
        __syncthreads();
    }

    // ---- epilogue: O (already normalized) -> Og (B,L,D) bf16 ----
    const int q0 = qt * 128 + wid * 32;
#pragma unroll
    for (int mi = 0; mi < 2; ++mi)
#pragma unroll
        for (int nt = 0; nt < 4; ++nt)
#pragma unroll
            for (int r = 0; r < 4; ++r) {
                int qrow = q0 + mi * 16 + qd * 4 + r;
                int dk = nt * 16 + ln;
                size_t oi = ((size_t)b * 2048 + qrow) * 1024 + h * 64 + dk;
                Og[oi] = f2bf(oacc[mi][nt][r]);
            }
}

// ---------------------------------------------------------------------------
extern "C" void kernel_launch(void* const* d_in, const int* in_sizes, int n_in,
                              void* d_out, int out_size, void* d_ws, size_t ws_size,
                              hipStream_t stream)
{
    (void)in_sizes; (void)n_in; (void)out_size; (void)ws_size;
    const float* q     = (const float*)d_in[0];
    const float* k     = (const float*)d_in[1];
    const float* v     = (const float*)d_in[2];
    const float* sem   = (const float*)d_in[3];
    const int*   mask  = (const int*)d_in[4];
    const float* w_q   = (const float*)d_in[5];
    const float* b_q   = (const float*)d_in[6];
    const float* w_k   = (const float*)d_in[7];
    const float* b_k   = (const float*)d_in[8];
    const float* w_v   = (const float*)d_in[9];
    const float* b_v   = (const float*)d_in[10];
    const float* w_sem = (const float*)d_in[11];
    const float* b_sem = (const float*)d_in[12];
    const float* w_out = (const float*)d_in[13];
    const float* b_out = (const float*)d_in[14];

    const size_t NE = (size_t)8192 * 1024;
    unsigned short* semh = (unsigned short*)d_ws;
    unsigned short* qh   = semh + NE;
    unsigned short* kh   = qh + NE;
    unsigned short* vh   = kh + NE;
    unsigned short* Og   = vh + NE;

    float* outp  = (float*)d_out;
    float* attnp = outp + NE;

    dim3 gg(8, 64), bb(256);
    // sem projection (head layout)
    hipLaunchKernelGGL((gemm_nt_kernel<0, 0>), gg, bb, 0, stream,
                       (const void*)sem, w_sem, b_sem, (const unsigned short*)nullptr,
                       (void*)semh, 1.0f);
    // q projection, scaled by 1/sqrt(64)
    hipLaunchKernelGGL((gemm_nt_kernel<0, 0>), gg, bb, 0, stream,
                       (const void*)q, w_q, b_q, (const unsigned short*)nullptr,
                       (void*)qh, 0.125f);
    // k projection + sem
    hipLaunchKernelGGL((gemm_nt_kernel<0, 0>), gg, bb, 0, stream,
                       (const void*)k, w_k, b_k, semh, (void*)kh, 1.0f);
    // v projection + sem
    hipLaunchKernelGGL((gemm_nt_kernel<0, 0>), gg, bb, 0, stream,
                       (const void*)v, w_v, b_v, semh, (void*)vh, 1.0f);
    // fused attention
    hipLaunchKernelGGL(attn_kernel, dim3(16, 64), bb, 0, stream,
                       qh, kh, vh, mask, attnp, Og);
    // output projection (fp32 out)
    hipLaunchKernelGGL((gemm_nt_kernel<1, 1>), gg, bb, 0, stream,
                       (const void*)Og, w_out, b_out, (const unsigned short*)nullptr,
                       (void*)outp, 1.0f);
}